// Round 6
// baseline (836.902 us; speedup 1.0000x reference)
//
#include <hip/hip_runtime.h>

// Problem: bs=8, seq=16, hw=32*32=1024, ck=256, cv=3, steps=seq-1=15
// Inputs fp32: k[8][16][1024][256], v[8][16][1024][3], attention[8][16][1024],
//              seq_mask int32[8][16].  Outputs fp32: out_v ++ gt.
//
// R6: mat-split attn blocks (grid z: 0=sim_k,1=sim_m) with deferred combine.
// Each attn block fully normalizes its softmax -> res[lb][q][3]; the NEXT
// update_state does rec = 0.9*resK + 0.1*resM, out/pv/mask epilogue.
// V staged in LDS; A-frags half-buffered; VGPR<=128 for 2 blocks/CU.
#define BS 8
#define SEQ 16
#define HW 1024
#define CK 256
#define CV 3
#define STEPS 15

#define SKP 264   // padded fp16 LDS row stride (256+8)

typedef unsigned short u16;
typedef _Float16 half8 __attribute__((ext_vector_type(8)));  // MFMA A/B frag
typedef float floatx4 __attribute__((ext_vector_type(4)));   // MFMA C/D frag

__device__ __forceinline__ u16 f2h(float f) {
  _Float16 h = (_Float16)f;
  return __builtin_bit_cast(unsigned short, h);
}
__device__ __forceinline__ float h2f(u16 u) {
  _Float16 h = __builtin_bit_cast(_Float16, u);
  return (float)h;
}

// ---- prep (once per pass): khA = fp16(k[:,0]), m_kh = 0, m_v = 0 ----
__global__ __launch_bounds__(256) void prep(const float* __restrict__ k,
                                            u16* __restrict__ kh0,
                                            u16* __restrict__ m_kh,
                                            float* __restrict__ m_v,
                                            int b0, int nb) {
  long idx = (long)blockIdx.x * 256 + threadIdx.x;
  long stride = (long)gridDim.x * 256;
  const long HC8 = (long)HW * CK / 8;
  const long nk8 = (long)nb * HC8;
  for (long i = idx; i < nk8; i += stride) {
    long lb = i / HC8, r = i - lb * HC8;
    const float* src = k + (long)(b0 + lb) * SEQ * HW * CK + r * 8;  // step-0 tile
    float4 a = *(const float4*)src;
    float4 b4 = *(const float4*)(src + 4);
    u16 t[8] = {f2h(a.x), f2h(a.y), f2h(a.z), f2h(a.w),
                f2h(b4.x), f2h(b4.y), f2h(b4.z), f2h(b4.w)};
    *(int4*)(kh0 + i * 8) = *(const int4*)t;
  }
  int4 z = {0, 0, 0, 0};
  for (long i = idx; i < nk8; i += stride) *(int4*)(m_kh + i * 8) = z;
  const long nv = (long)nb * HW * CV;
  for (long i = idx; i < nv; i += stride) m_v[i] = 0.0f;
}

// ---------------- gt = v[:,1:] (pure copy, fp32) ----------------
__global__ __launch_bounds__(256) void gt_copy(const float* __restrict__ v,
                                               float* __restrict__ out) {
  int idx = blockIdx.x * 256 + threadIdx.x;
  const int n = BS * STEPS * HW * CV;            // 368,640
  if (idx >= n) return;
  int b = idx / (STEPS * HW * CV);
  int r = idx - b * (STEPS * HW * CV);
  int i = r / (HW * CV);
  int rr = r - i * (HW * CV);
  out[n + idx] = v[(long)(b * SEQ + i + 1) * (HW * CV) + rr];
}

// --------- per-step: combine epilogue of step-1, EMA m_kh/m_v, kh convert ---------
// grid (nb,32), 256 thr: thread (pl=tid>>3, s=tid&7) -> row pb*32+pl, cols [s*32,+32)
__global__ __launch_bounds__(256) void update_state(
    const float* __restrict__ k, const float* __restrict__ v,
    const float* __restrict__ att, const int* __restrict__ seq_mask,
    const float* __restrict__ resK, const float* __restrict__ resM,
    const u16* __restrict__ kh_cur, u16* __restrict__ kh_next,
    u16* __restrict__ m_kh, float* __restrict__ m_v,
    float* __restrict__ pv, float* __restrict__ out, int step, int b0)
{
  const int lb = blockIdx.x, b = b0 + lb, pb = blockIdx.y;
  const int tid = threadIdx.x;
  const int pl = tid >> 3, s = tid & 7;
  const int p = pb * 32 + pl;

  { // fp32 -> fp16 conversion of next step's k tile (k[:, step+1])
    const float* src = k + ((long)(b * SEQ + step + 1) * HW + p) * CK + s * 32;
    u16* dst = kh_next + ((long)lb * HW + p) * CK + s * 32;
    #pragma unroll
    for (int c = 0; c < 32; c += 8) {
      float4 a = *(const float4*)(src + c);
      float4 b4 = *(const float4*)(src + c + 4);
      u16 t[8] = {f2h(a.x), f2h(a.y), f2h(a.z), f2h(a.w),
                  f2h(b4.x), f2h(b4.y), f2h(b4.z), f2h(b4.w)};
      *(int4*)(dst + c) = *(const int4*)t;
    }
  }

  float a = att[(long)(b * SEQ + step) * HW + p];
  float g = 1.0f / (1.0f + __expf(-a));
  float og = 1.0f - g;

  // EMA of m_kh (fp16 state, fp32 math)
  const u16* krow = kh_cur + ((long)lb * HW + p) * CK + s * 32;
  u16* mrow = m_kh + ((long)lb * HW + p) * CK + s * 32;
  #pragma unroll
  for (int c = 0; c < 32; c += 8) {
    int4 kr = *(const int4*)(krow + c);
    int4 mr = *(const int4*)(mrow + c);
    const u16* ku = (const u16*)&kr;
    const u16* mu = (const u16*)&mr;
    u16 nh[8];
    #pragma unroll
    for (int j = 0; j < 8; ++j)
      nh[j] = f2h(fmaf(g, h2f(ku[j]), og * h2f(mu[j])));
    *(int4*)(mrow + c) = *(const int4*)&nh[0];
  }

  if (s == 0) {  // epilogue of step-1 + prev_v carry + m_v EMA
    float pvv[3];
    if (step == 0) {
      const float* vr = v + ((long)b * SEQ * HW + p) * CV;   // v[b][0][p]
      pvv[0] = vr[0]; pvv[1] = vr[1]; pvv[2] = vr[2];
    } else {
      const float* rk = resK + ((long)lb * HW + p) * CV;
      const float* rm = resM + ((long)lb * HW + p) * CV;
      const int maskv = seq_mask[b * SEQ + step - 1];
      float* ov = out + ((long)(b * STEPS + step - 1) * HW + p) * CV;
      const float* vr = v + ((long)(b * SEQ + step - 1) * HW + p) * CV;
      #pragma unroll
      for (int c = 0; c < CV; ++c) {
        float rec = 0.9f * rk[c] + 0.1f * rm[c];   // COEF_MEMORY = 0.1
        ov[c] = rec;
        pvv[c] = maskv ? vr[c] : rec;
      }
    }
    float* pvp = pv + ((long)lb * HW + p) * CV;
    float* mvp = m_v + ((long)lb * HW + p) * CV;
    #pragma unroll
    for (int c = 0; c < CV; ++c) {
      pvp[c] = pvv[c];
      mvp[c] = fmaf(g, pvv[c], og * mvp[c]);
    }
  }
}

// --------- per-step single-matrix attention block (mat = blockIdx.z) ---------
// grid (nb, 32, 2), 512 thr = 8 waves. Wave w owns p-range [w*128, +128).
// MFMA: A = p-rows (streamed from ws), B = q-tile (regs).
// D[p][q]: q = lane&15 (+16*qi), p = (lane>>4)*4 + reg.
__global__ __launch_bounds__(512, 4) void attn_step(
    const u16* __restrict__ kh_c, const u16* __restrict__ kh_n,
    const u16* __restrict__ m_kh,
    const float* __restrict__ pv, const float* __restrict__ m_v,
    float* __restrict__ resK, float* __restrict__ resM, int b0)
{
  __shared__ u16 Kq[32 * SKP];       // q-tile fp16 (16.9 KB)
  __shared__ float Vs[HW * 4];       // V tile, padded 4 floats/row (16 KB)
  __shared__ float Mg[8][32][5];     // per-wave partials (5 KB)

  const int lb = blockIdx.x;
  const int q0 = blockIdx.y * 32;
  const int mat = blockIdx.z;
  const int tid = threadIdx.x;
  const int w = tid >> 6, lane = tid & 63;
  const int r = lane & 15, rg = lane >> 4;

  const u16* Kn = kh_n + (long)lb * HW * CK;                       // q side
  const u16* Ab = (mat ? m_kh : kh_c) + (long)lb * HW * CK;        // p side
  const float* Vsrc = (mat ? m_v : pv) + (long)lb * HW * CV;
  float* res = mat ? resM : resK;

  { // stage q-tile: 1024 16B-chunks over 512 threads
    #pragma unroll
    for (int j = 0; j < 2; ++j) {
      int c = tid + j * 512;
      int row = c >> 5, off = (c & 31) * 8;
      *(int4*)&Kq[row * SKP + off] = *(const int4*)(Kn + (long)(q0 + row) * CK + off);
    }
  }
  { // stage V: 1024 rows x 3 -> padded 4
    #pragma unroll
    for (int j = 0; j < 2; ++j) {
      int row = tid + j * 512;
      const float* vp = Vsrc + (long)row * CV;
      float* d = &Vs[row * 4];
      d[0] = vp[0]; d[1] = vp[1]; d[2] = vp[2]; d[3] = 0.f;
    }
  }
  __syncthreads();

  // B fragments (q-tile) in registers: 2 q-subtiles x 8 k-steps (64 VGPR)
  half8 Bq[2][8];
  #pragma unroll
  for (int qi = 0; qi < 2; ++qi)
    #pragma unroll
    for (int kk = 0; kk < 8; ++kk)
      Bq[qi][kk] = *(const half8*)&Kq[(qi * 16 + r) * SKP + kk * 32 + rg * 8];

  float mx[2] = {-1e30f, -1e30f}, l[2] = {0.f, 0.f};
  float acc[2][3] = {{0.f, 0.f, 0.f}, {0.f, 0.f, 0.f}};

  // 8 groups of 16 p-rows: pr = w*128 + g*16
  for (int gidx = 0; gidx < 8; ++gidx) {
    const int pr = w * 128 + gidx * 16;
    const u16* Arow = Ab + (long)(pr + r) * CK + rg * 8;

    floatx4 c0 = {0.f, 0.f, 0.f, 0.f}, c1 = {0.f, 0.f, 0.f, 0.f};
    #pragma unroll
    for (int h = 0; h < 2; ++h) {   // half-buffered A (16 VGPR)
      half8 A[4];
      #pragma unroll
      for (int kk = 0; kk < 4; ++kk)
        A[kk] = *(const half8*)(Arow + (h * 4 + kk) * 32);
      #pragma unroll
      for (int kk = 0; kk < 4; ++kk) {
        c0 = __builtin_amdgcn_mfma_f32_16x16x32_f16(A[kk], Bq[0][h * 4 + kk], c0, 0, 0, 0);
        c1 = __builtin_amdgcn_mfma_f32_16x16x32_f16(A[kk], Bq[1][h * 4 + kk], c1, 0, 0, 0);
      }
    }

    // V for this lane's 4 p-rows (LDS, broadcast across the 16 lanes of rg)
    float4 Vv[4];
    #pragma unroll
    for (int j = 0; j < 4; ++j)
      Vv[j] = *(const float4*)&Vs[(pr + rg * 4 + j) * 4];

    #pragma unroll
    for (int qi = 0; qi < 2; ++qi) {
      floatx4 cc = qi ? c1 : c0;
      float tmax = fmaxf(fmaxf(cc[0], cc[1]), fmaxf(cc[2], cc[3]));
      tmax = fmaxf(tmax, mx[qi]);
      float sc = __expf(mx[qi] - tmax);
      l[qi] *= sc;
      acc[qi][0] *= sc; acc[qi][1] *= sc; acc[qi][2] *= sc;
      #pragma unroll
      for (int j = 0; j < 4; ++j) {
        float e = __expf(cc[j] - tmax);
        l[qi] += e;
        acc[qi][0] = fmaf(e, Vv[j].x, acc[qi][0]);
        acc[qi][1] = fmaf(e, Vv[j].y, acc[qi][1]);
        acc[qi][2] = fmaf(e, Vv[j].z, acc[qi][2]);
      }
      mx[qi] = tmax;
    }
  }

  // merge 4 rowgroup partials (lanes r, r+16, r+32, r+48)
  #pragma unroll
  for (int off = 16; off <= 32; off <<= 1) {
    #pragma unroll
    for (int qi = 0; qi < 2; ++qi) {
      float m2 = __shfl_xor(mx[qi], off);
      float l2 = __shfl_xor(l[qi], off);
      float b0s = __shfl_xor(acc[qi][0], off);
      float b1s = __shfl_xor(acc[qi][1], off);
      float b2s = __shfl_xor(acc[qi][2], off);
      float mn = fmaxf(mx[qi], m2);
      float e1 = __expf(mx[qi] - mn), e2 = __expf(m2 - mn);
      l[qi] = l[qi] * e1 + l2 * e2;
      acc[qi][0] = acc[qi][0] * e1 + b0s * e2;
      acc[qi][1] = acc[qi][1] * e1 + b1s * e2;
      acc[qi][2] = acc[qi][2] * e1 + b2s * e2;
      mx[qi] = mn;
    }
  }
  if (rg == 0) {
    #pragma unroll
    for (int qi = 0; qi < 2; ++qi) {
      float* d = Mg[w][qi * 16 + r];
      d[0] = mx[qi]; d[1] = l[qi];
      d[2] = acc[qi][0]; d[3] = acc[qi][1]; d[4] = acc[qi][2];
    }
  }
  __syncthreads();

  // cross-wave merge + normalized per-mat result
  if (tid < 32) {
    const int q = tid;
    float M = -1e30f, L = 0.f, A0 = 0.f, A1 = 0.f, A2 = 0.f;
    #pragma unroll
    for (int ww = 0; ww < 8; ++ww) {
      const float* d = Mg[ww][q];
      float mn = fmaxf(M, d[0]);
      float e1 = __expf(M - mn), e2 = __expf(d[0] - mn);
      L = L * e1 + d[1] * e2;
      A0 = A0 * e1 + d[2] * e2;
      A1 = A1 * e1 + d[3] * e2;
      A2 = A2 * e1 + d[4] * e2;
      M = mn;
    }
    float iL = 1.0f / L;
    float* dst = res + ((long)lb * HW + q0 + q) * CV;
    dst[0] = A0 * iL; dst[1] = A1 * iL; dst[2] = A2 * iL;
  }
}

// ---- final combine: out[:, STEPS-1] = 0.9*resK + 0.1*resM ----
__global__ __launch_bounds__(256) void final_combine(
    const float* __restrict__ resK, const float* __restrict__ resM,
    float* __restrict__ out, int b0, int nb) {
  int idx = blockIdx.x * 256 + threadIdx.x;
  const int n = nb * HW * CV;
  if (idx >= n) return;
  int lb = idx / (HW * CV);
  int r = idx - lb * (HW * CV);
  out[((long)((b0 + lb) * STEPS + STEPS - 1) * HW) * CV + r] =
      0.9f * resK[idx] + 0.1f * resM[idx];
}

extern "C" void kernel_launch(void* const* d_in, const int* in_sizes, int n_in,
                              void* d_out, int out_size, void* d_ws, size_t ws_size,
                              hipStream_t stream) {
  const float* k   = (const float*)d_in[0];
  const float* v   = (const float*)d_in[1];
  const float* att = (const float*)d_in[2];
  const int* seq_mask = (const int*)d_in[3];
  float* out = (float*)d_out;

  // per-batch ws: khA/khB/m_kh 512KB each + m_v/pv/resK/resM 12KB each
  const size_t KHT_B = (size_t)HW * CK * 2;       // 524,288
  const size_t SV_B  = (size_t)HW * CV * 4;       //  12,288
  const size_t PER_B = 3 * KHT_B + 4 * SV_B;      // 1,622,016

  int nb = (int)(ws_size / PER_B);
  if (nb < 1) nb = 1;
  if (nb > BS) nb = BS;

  char* ws = (char*)d_ws;

  gt_copy<<<1440, 256, 0, stream>>>(v, out);

  for (int b0 = 0; b0 < BS; b0 += nb) {
    int nbp = (b0 + nb <= BS) ? nb : (BS - b0);
    u16*   khA  = (u16*)(ws + 0);
    u16*   khB  = (u16*)(ws + (size_t)nb * KHT_B);
    u16*   m_kh = (u16*)(ws + (size_t)nb * KHT_B * 2);
    float* m_v  = (float*)(ws + (size_t)nb * KHT_B * 3);
    float* pv   = (float*)(ws + (size_t)nb * (KHT_B * 3 + SV_B));
    float* resK = (float*)(ws + (size_t)nb * (KHT_B * 3 + SV_B * 2));
    float* resM = (float*)(ws + (size_t)nb * (KHT_B * 3 + SV_B * 3));

    prep<<<1024, 256, 0, stream>>>(k, khA, m_kh, m_v, b0, nbp);

    for (int i = 0; i < STEPS; ++i) {
      u16* khc = (i & 1) ? khB : khA;   // holds fp16 k[:, i]
      u16* khn = (i & 1) ? khA : khB;   // update writes fp16 k[:, i+1]
      update_state<<<dim3(nbp, 32), 256, 0, stream>>>(
          k, v, att, seq_mask, resK, resM, khc, khn, m_kh, m_v, pv, out, i, b0);
      attn_step<<<dim3(nbp, 32, 2), 512, 0, stream>>>(
          khc, khn, m_kh, pv, m_v, resK, resM, b0);
    }
    final_combine<<<nbp * 12, 256, 0, stream>>>(resK, resM, out, b0, nbp);
  }
}